// Round 4
// baseline (691.566 us; speedup 1.0000x reference)
//
#include <hip/hip_runtime.h>
#include <stdint.h>

// out[8192,4096] = x[8192,4096] @ (A[4096,16] @ B[16,4096]), ALL FP32.
// R3: two simple kernels through d_ws (T = x@A, 8192x16 fp32 = 512 KB).
// K1: lane-private contiguous A rows (no scatter), coalesced float4 X,
//     deep MLP (18 loads in flight/step), butterfly reduce, lane-0 stores.
//     No LDS, no barriers, no dynamic register indexing.
// K2: R1-proven phase B — T tile staged to LDS once (write -> barrier ->
//     read-only), B frags in regs, coalesced float4 stores.

#define KD 4096
#define ND 4096
#define NR 16
#define BLK 256

// ---------------- K1: T = X @ A ----------------
#define RPW1 2                 // rows per wave
#define MB1  (4 * RPW1)        // 8 rows per block (4 waves)

__global__ __launch_bounds__(BLK, 4)
void lora_xa(const float* __restrict__ X,
             const float* __restrict__ A,
             float* __restrict__ T)
{
    const int tid  = threadIdx.x;
    const int wv   = tid >> 6;
    const int lane = tid & 63;
    const size_t m0 = (size_t)blockIdx.x * MB1 + wv * RPW1;  // this wave's rows

    float acc[RPW1][NR];
    #pragma unroll
    for (int i = 0; i < RPW1; ++i)
        #pragma unroll
        for (int r = 0; r < NR; ++r) acc[i][r] = 0.f;

    #pragma unroll 1
    for (int s = 0; s < KD / 256; ++s) {      // 16 steps; lane owns k0..k0+3
        const int k0 = s * 256 + lane * 4;
        float4 xv[RPW1];
        #pragma unroll
        for (int i = 0; i < RPW1; ++i)
            xv[i] = *reinterpret_cast<const float4*>(X + (m0 + i) * KD + k0);

        #pragma unroll
        for (int j = 0; j < 4; ++j) {
            // Lane-private A row k0+j: contiguous 64 B, fully consumed by this lane.
            const float4 a0 = *reinterpret_cast<const float4*>(A + (size_t)(k0 + j) * NR + 0);
            const float4 a1 = *reinterpret_cast<const float4*>(A + (size_t)(k0 + j) * NR + 4);
            const float4 a2 = *reinterpret_cast<const float4*>(A + (size_t)(k0 + j) * NR + 8);
            const float4 a3 = *reinterpret_cast<const float4*>(A + (size_t)(k0 + j) * NR + 12);
            const float af[NR] = { a0.x, a0.y, a0.z, a0.w,
                                   a1.x, a1.y, a1.z, a1.w,
                                   a2.x, a2.y, a2.z, a2.w,
                                   a3.x, a3.y, a3.z, a3.w };
            #pragma unroll
            for (int i = 0; i < RPW1; ++i) {
                const float xf = (&xv[i].x)[j];    // constant index after unroll
                #pragma unroll
                for (int r = 0; r < NR; ++r)
                    acc[i][r] = fmaf(xf, af[r], acc[i][r]);
            }
        }
    }

    // Butterfly reduce across the 64-lane wave (R1-proven)
    #pragma unroll
    for (int off = 32; off > 0; off >>= 1)
        #pragma unroll
        for (int i = 0; i < RPW1; ++i)
            #pragma unroll
            for (int r = 0; r < NR; ++r)
                acc[i][r] += __shfl_xor(acc[i][r], off, 64);

    if (lane == 0) {       // constant-index stores only
        #pragma unroll
        for (int i = 0; i < RPW1; ++i)
            #pragma unroll
            for (int r = 0; r < NR; ++r)
                T[(m0 + i) * NR + r] = acc[i][r];
    }
}

// ---------------- K2: O = T @ B ----------------
#define MB2 8                  // rows per block

__global__ __launch_bounds__(BLK, 4)
void lora_tb(const float* __restrict__ T,
             const float* __restrict__ Bm,
             float* __restrict__ O)
{
    __shared__ float Ts[MB2][NR];
    const int tid = threadIdx.x;
    const size_t m0 = (size_t)blockIdx.x * MB2;

    if (tid < (MB2 * NR) / 4) {     // 32 threads stage the 512-B T tile
        const float4 v = *reinterpret_cast<const float4*>(T + m0 * NR + tid * 4);
        *reinterpret_cast<float4*>(&Ts[0][0] + tid * 4) = v;
    }
    __syncthreads();                 // single write->barrier->read-only sync

    #pragma unroll 1
    for (int p = 0; p < ND / (BLK * 4); ++p) {   // 4 passes, 4 cols/thread
        const int j0 = p * (BLK * 4) + tid * 4;
        float bf[NR][4];
        #pragma unroll
        for (int r = 0; r < NR; ++r) {
            const float4 bv = *reinterpret_cast<const float4*>(Bm + (size_t)r * ND + j0);
            bf[r][0] = bv.x; bf[r][1] = bv.y; bf[r][2] = bv.z; bf[r][3] = bv.w;
        }
        #pragma unroll
        for (int m = 0; m < MB2; ++m) {
            const float4 t0 = *reinterpret_cast<const float4*>(&Ts[m][0]);
            const float4 t1 = *reinterpret_cast<const float4*>(&Ts[m][4]);
            const float4 t2 = *reinterpret_cast<const float4*>(&Ts[m][8]);
            const float4 t3 = *reinterpret_cast<const float4*>(&Ts[m][12]);
            const float tr[NR] = { t0.x, t0.y, t0.z, t0.w,
                                   t1.x, t1.y, t1.z, t1.w,
                                   t2.x, t2.y, t2.z, t2.w,
                                   t3.x, t3.y, t3.z, t3.w };
            float o[4] = {0.f, 0.f, 0.f, 0.f};
            #pragma unroll
            for (int r = 0; r < NR; ++r)
                #pragma unroll
                for (int c = 0; c < 4; ++c)
                    o[c] = fmaf(tr[r], bf[r][c], o[c]);

            *reinterpret_cast<float4*>(O + (m0 + m) * ND + j0) =
                make_float4(o[0], o[1], o[2], o[3]);
        }
    }
}

extern "C" void kernel_launch(void* const* d_in, const int* in_sizes, int n_in,
                              void* d_out, int out_size, void* d_ws, size_t ws_size,
                              hipStream_t stream) {
    const float* X  = (const float*)d_in[0];   // [4,2048,4096] fp32
    const float* A  = (const float*)d_in[1];   // [4096,16]     fp32
    const float* Bm = (const float*)d_in[2];   // [16,4096]     fp32
    float* O = (float*)d_out;                  // [4,2048,4096] fp32
    float* T = (float*)d_ws;                   // [8192,16]     fp32, 512 KB scratch

    lora_xa<<<8192 / MB1, BLK, 0, stream>>>(X, A, T);
    lora_tb<<<8192 / MB2, BLK, 0, stream>>>(T, Bm, O);
}